// Round 1
// baseline (312.642 us; speedup 1.0000x reference)
//
#include <hip/hip_runtime.h>

#define W      512
#define NSTEP  100
#define TILE   32
// canvas tile with 1-pixel halo, padded stride to dodge bank conflicts
#define CROWS  (TILE + 2)              // 34
#define CSTRIDE (TILE + 3)             // 35

__global__ __launch_bounds__(256) void qbc_kernel(
    const float* __restrict__ strokes, float* __restrict__ out, int B)
{
    #pragma clang fp contract(off)     // match XLA per-op IEEE fp32 (no fma fusion)

    const int b   = blockIdx.z;
    const int ti0 = blockIdx.y * TILE; // row origin (grid_x / i axis)
    const int tj0 = blockIdx.x * TILE; // col origin (grid_y / j axis)
    const int tid = threadIdx.x;

    __shared__ float4 steps[NSTEP];
    __shared__ float4 clist[NSTEP];
    __shared__ int    flags[NSTEP];
    __shared__ int    nlist;
    __shared__ float  canvas[CROWS * CSTRIDE];

    // ---- Phase A: per-step params (exactly mirrors the reference fp32 ops) ----
    if (tid < NSTEP) {
        const float* s = strokes + b * 10;
        float P0x = s[0], P0y = s[1];
        float m1x = s[2], m1y = s[3];
        float P2x = s[4], P2y = s[5];
        // P1 = P0 + (P2 - P0) * P1   (before scaling)
        float P1x = P0x + (P2x - P0x) * m1x;
        float P1y = P0y + (P2y - P0y) * m1y;
        // scale(v) = v*511 + 0.5
        float X0 = P0x * 511.0f + 0.5f;
        float X1 = P1x * 511.0f + 0.5f;
        float X2 = P2x * 511.0f + 0.5f;
        float Y0 = P0y * 511.0f + 0.5f;
        float Y1 = P1y * 511.0f + 0.5f;
        float Y2 = P2y * 511.0f + 0.5f;
        float r0 = 1.0f + s[6] * 128.0f;
        float r2 = 1.0f + s[7] * 128.0f;
        float c0 = s[8], c2 = s[9];
        // t = iota * (1/99)  (jnp.linspace fp32 semantics)
        float tf = (float)tid * (1.0f / 99.0f);
        float mt = 1.0f - tf;
        float s0 = mt * mt;
        float s1 = (2.0f * mt) * tf;
        float s2 = tf * tf;
        float ex0 = X0 * s0, ex1 = X1 * s1, ex2 = X2 * s2;
        float X   = (ex0 + ex1) + ex2;
        float ey0 = Y0 * s0, ey1 = Y1 * s1, ey2 = Y2 * s2;
        float Y   = (ey0 + ey1) + ey2;
        float ra  = r0 * mt, rb = r2 * tf;
        float rt  = ra + rb;
        float r2t = rt * rt;
        float ca  = c0 * mt, cb = c2 * tf;
        float ct  = ca + cb;
        steps[tid] = make_float4(X, Y, r2t, ct);

        // conservative circle-vs-haloed-tile-rect test (margin >> fp noise)
        float lo_i = (float)(ti0 - 1), hi_i = (float)(ti0 + TILE);
        float lo_j = (float)(tj0 - 1), hi_j = (float)(tj0 + TILE);
        float ci = fminf(fmaxf(X, lo_i), hi_i);
        float cj = fminf(fmaxf(Y, lo_j), hi_j);
        float di = X - ci, dj = Y - cj;
        flags[tid] = ((di * di + dj * dj) < (r2t + 4.0f)) ? 1 : 0;
    }
    __syncthreads();

    // ---- Phase B: order-preserving compaction (thread 0, 100 iters, cheap) ----
    if (tid == 0) {
        int n = 0;
        for (int t = 0; t < NSTEP; ++t)
            if (flags[t]) clist[n++] = steps[t];
        nlist = n;
    }
    __syncthreads();
    const int n = nlist;

    // ---- Phase C: rasterize 34x34 haloed canvas tile into LDS ----
    for (int idx = tid; idx < CROWS * CROWS; idx += 256) {
        int row = idx / CROWS;
        int col = idx - row * CROWS;
        int gi = ti0 - 1 + row;
        int gj = tj0 - 1 + col;
        float val = 0.0f;                       // zero canvas + zero conv padding
        if (gi >= 0 && gi < W && gj >= 0 && gj < W) {
            float fi = (float)gi, fj = (float)gj;
            for (int k = n - 1; k >= 0; --k) {  // last-write-wins -> first hit from back
                float4 st = clist[k];
                float dx  = fi - st.x;
                float dy  = fj - st.y;
                float dx2 = dx * dx;
                float dy2 = dy * dy;
                float d2  = dx2 + dy2;          // same assoc order as reference
                if (d2 < st.z) { val = st.w; break; }
            }
        }
        canvas[row * CSTRIDE + col] = val;
    }
    __syncthreads();

    // ---- Phase D: fused 3x3 Gaussian blur + (1 - x), coalesced store ----
    const double e2d = 0.13533528323661270;     // exp(-2)
    const double e4d = 0.018315638888734179;    // exp(-4)
    const double Sd  = 1.0 + 4.0 * e2d + 4.0 * e4d;
    const float WC = (float)(1.0 / Sd);
    const float WE = (float)(e2d / Sd);
    const float WK = (float)(e4d / Sd);

    int c  = tid & (TILE - 1);
    int r0 = tid >> 5;                          // 0..7
    for (int kk = 0; kk < 4; ++kk) {
        int r = r0 + kk * 8;
        const float* top = &canvas[r * CSTRIDE + c];
        const float* mid = top + CSTRIDE;
        const float* bot = mid + CSTRIDE;
        float acc = WC * mid[1]
                  + WE * ((top[1] + bot[1]) + (mid[0] + mid[2]))
                  + WK * ((top[0] + top[2]) + (bot[0] + bot[2]));
        int oi = ti0 + r;
        int oj = tj0 + c;
        out[((size_t)b * W + (size_t)oi) * W + (size_t)oj] = 1.0f - acc;
    }
}

extern "C" void kernel_launch(void* const* d_in, const int* in_sizes, int n_in,
                              void* d_out, int out_size, void* d_ws, size_t ws_size,
                              hipStream_t stream) {
    const float* strokes = (const float*)d_in[0];
    float* out = (float*)d_out;
    int B = in_sizes[0] / 10;
    dim3 grid(W / TILE, W / TILE, B);
    qbc_kernel<<<grid, dim3(256), 0, stream>>>(strokes, out, B);
}

// Round 2
// 221.973 us; speedup vs baseline: 1.4085x; 1.4085x over previous
//
#include <hip/hip_runtime.h>

#define W       512
#define NSTEP   100
#define TILE    32
#define CROWS   (TILE + 2)             // 34 (haloed tile)
#define CPX     (CROWS * CROWS)        // 1156
#define PER_WAVE 289                   // 1156 / 4 waves (exact)
#define PPT     5                      // ceil(289/64) pixel slots per thread

__global__ __launch_bounds__(256) void qbc_kernel(
    const float* __restrict__ strokes, float* __restrict__ out, int B)
{
    #pragma clang fp contract(off)     // match XLA per-op IEEE fp32 (no fma fusion)

    const int b   = blockIdx.z;
    const int ti0 = blockIdx.y * TILE; // row origin (grid_x / i axis)
    const int tj0 = blockIdx.x * TILE; // col origin (grid_y / j axis)
    const int tid = threadIdx.x;

    __shared__ float4 steps[NSTEP];
    __shared__ float4 clist[NSTEP];
    __shared__ int    flags[NSTEP];
    __shared__ int    nlist;
    __shared__ float  canvas[CPX];     // linear 34x34

    // ---- Phase A: per-step params (exactly mirrors the reference fp32 ops) ----
    if (tid < NSTEP) {
        const float* s = strokes + b * 10;
        float P0x = s[0], P0y = s[1];
        float m1x = s[2], m1y = s[3];
        float P2x = s[4], P2y = s[5];
        float P1x = P0x + (P2x - P0x) * m1x;   // P1 = P0 + (P2-P0)*P1
        float P1y = P0y + (P2y - P0y) * m1y;
        float X0 = P0x * 511.0f + 0.5f;        // scale(v) = v*511 + 0.5
        float X1 = P1x * 511.0f + 0.5f;
        float X2 = P2x * 511.0f + 0.5f;
        float Y0 = P0y * 511.0f + 0.5f;
        float Y1 = P1y * 511.0f + 0.5f;
        float Y2 = P2y * 511.0f + 0.5f;
        float r0 = 1.0f + s[6] * 128.0f;
        float r2 = 1.0f + s[7] * 128.0f;
        float c0 = s[8], c2 = s[9];
        float tf = (float)tid * (1.0f / 99.0f); // jnp.linspace fp32 semantics
        float mt = 1.0f - tf;
        float s0 = mt * mt;
        float s1 = (2.0f * mt) * tf;
        float s2 = tf * tf;
        float ex0 = X0 * s0, ex1 = X1 * s1, ex2 = X2 * s2;
        float X   = (ex0 + ex1) + ex2;
        float ey0 = Y0 * s0, ey1 = Y1 * s1, ey2 = Y2 * s2;
        float Y   = (ey0 + ey1) + ey2;
        float ra  = r0 * mt, rb = r2 * tf;
        float rt  = ra + rb;
        float r2t = rt * rt;
        float ca  = c0 * mt, cb = c2 * tf;
        float ct  = ca + cb;
        steps[tid] = make_float4(X, Y, r2t, ct);

        // conservative circle-vs-haloed-tile-rect test (margin >> fp noise)
        float lo_i = (float)(ti0 - 1), hi_i = (float)(ti0 + TILE);
        float lo_j = (float)(tj0 - 1), hi_j = (float)(tj0 + TILE);
        float ci = fminf(fmaxf(X, lo_i), hi_i);
        float cj = fminf(fmaxf(Y, lo_j), hi_j);
        float di = X - ci, dj = Y - cj;
        flags[tid] = ((di * di + dj * dj) < (r2t + 4.0f)) ? 1 : 0;
    }
    __syncthreads();

    // ---- Phase B: order-preserving compaction, wave 0, ballot prefix-sum ----
    if (tid < 64) {
        bool f0 = flags[tid] != 0;                       // steps 0..63
        unsigned long long m0 = __ballot(f0);
        int p0 = __popcll(m0 & ((1ull << tid) - 1ull));
        if (f0) clist[p0] = steps[tid];
        int c1 = __popcll(m0);
        int t1 = 64 + tid;                               // steps 64..99
        bool f1 = (t1 < NSTEP) && (flags[t1] != 0);
        unsigned long long m1 = __ballot(f1);
        int p1 = __popcll(m1 & ((1ull << tid) - 1ull));
        if (f1) clist[c1 + p1] = steps[t1];
        if (tid == 0) nlist = c1 + __popcll(m1);
    }

    // ---- pixel setup (independent of compaction; before the barrier) ----
    const int wave = tid >> 6;
    const int lane = tid & 63;
    const int base = wave * PER_WAVE;

    float fi[PPT], fj[PPT], vals[PPT];
    bool  done[PPT], live[PPT];
    int   idxs[PPT];
    #pragma unroll
    for (int p = 0; p < PPT; ++p) {
        int off = lane + 64 * p;
        bool valid = off < PER_WAVE;
        int idx = base + (valid ? off : 0);
        idxs[p] = idx;
        live[p] = valid;
        int row = idx / CROWS;
        int col = idx - row * CROWS;
        int gi = ti0 - 1 + row;
        int gj = tj0 - 1 + col;
        bool inb = valid && (gi >= 0) && (gi < W) && (gj >= 0) && (gj < W);
        fi[p] = (float)gi;
        fj[p] = (float)gj;
        vals[p] = 0.0f;
        done[p] = !inb;                 // OOB halo & dead slots: nothing to do
    }
    __syncthreads();
    const int n = nlist;

    // ---- Phase C: backward branchless rasterize, wave-uniform early exit ----
    for (int k = n - 1; k >= 0; --k) {
        float4 st = clist[k];           // wave-uniform -> broadcast, no conflict
        bool all = true;
        #pragma unroll
        for (int p = 0; p < PPT; ++p) {
            float dx  = fi[p] - st.x;
            float dy  = fj[p] - st.y;
            float dx2 = dx * dx;
            float dy2 = dy * dy;
            float d2  = dx2 + dy2;      // same assoc order as reference
            bool hit  = d2 < st.z;
            vals[p]   = (hit && !done[p]) ? st.w : vals[p];
            done[p]   = done[p] || hit;
            all       = all && done[p];
        }
        if (__all(all ? 1 : 0)) break;  // uniform branch, no divergence
    }

    #pragma unroll
    for (int p = 0; p < PPT; ++p)
        if (live[p]) canvas[idxs[p]] = vals[p];
    __syncthreads();

    // ---- Phase D: fused 3x3 Gaussian blur + (1 - x), coalesced store ----
    const double e2d = 0.13533528323661270;     // exp(-2)
    const double e4d = 0.018315638888734179;    // exp(-4)
    const double Sd  = 1.0 + 4.0 * e2d + 4.0 * e4d;
    const float WC = (float)(1.0 / Sd);
    const float WE = (float)(e2d / Sd);
    const float WK = (float)(e4d / Sd);

    int c  = tid & (TILE - 1);
    int r0 = tid >> 5;                          // 0..7
    #pragma unroll
    for (int kk = 0; kk < 4; ++kk) {
        int r = r0 + kk * 8;
        const float* top = &canvas[r * CROWS + c];
        const float* mid = top + CROWS;
        const float* bot = mid + CROWS;
        float acc = WC * mid[1]
                  + WE * ((top[1] + bot[1]) + (mid[0] + mid[2]))
                  + WK * ((top[0] + top[2]) + (bot[0] + bot[2]));
        int oi = ti0 + r;
        int oj = tj0 + c;
        out[((size_t)b * W + (size_t)oi) * W + (size_t)oj] = 1.0f - acc;
    }
}

extern "C" void kernel_launch(void* const* d_in, const int* in_sizes, int n_in,
                              void* d_out, int out_size, void* d_ws, size_t ws_size,
                              hipStream_t stream) {
    const float* strokes = (const float*)d_in[0];
    float* out = (float*)d_out;
    int B = in_sizes[0] / 10;
    dim3 grid(W / TILE, W / TILE, B);
    qbc_kernel<<<grid, dim3(256), 0, stream>>>(strokes, out, B);
}